// Round 2
// baseline (331.542 us; speedup 1.0000x reference)
//
#include <hip/hip_runtime.h>

// Problem dims (from reference setup_inputs): T=256, B=128, I=512, H=512
#define T_STEPS 256
#define B_DIM   128
#define I_DIM   512
#define H_DIM   512
#define M_DIM   (T_STEPS * B_DIM)   // 32768 rows of the flattened GEMM

// GEMM tiling. 8x16 per-thread fragment: per k-step a wave does
// 6 ds_read_b128 per 128 FMAs -> LDS demand/FMA ratio 1.125 (was 1.5 with
// 8x8), lifting the VALUBusy ceiling from ~70% to ~89%.
#define BM 128
#define BN 256
#define BK 32
#define KTILES (I_DIM / BK)

// h[m][n] = sum_k x[m][k] * W[n][k] + b[n]
// A (x) is [M][K] row-major, Bw (W) is [N][K] row-major -> both K-major.
//
// LDS layout: k-major [BK][BM|BN] floats, no pad, XOR swizzle at float4
// granularity: physical_blk = logical_blk ^ rho(k), rho(k) = (k>>2)&7.
//  - staging writes: thread stages k-rows lk..lk+3 (lk = (tid&7)*4) so
//    rho = tid&7 is thread-constant; banks 2-way across the wave (free).
//  - A reads (blocks 2ty, 2ty+1): 4 broadcast addrs/inst, distinct bank
//    groups -> conflict-free.
//  - B reads (blocks {0,16,32,48}+tx): 16 addrs/inst, (tx&7)^rho hits each
//    bank group twice -> 2-way (free).
//
// Pipeline (2-phase, T14-style): global loads for tile t+1 are issued right
// after the LDS-write barrier, BEFORE computing tile t; the ~8K-cycle compute
// phase hides the HBM/L2 latency. One LDS buffer suffices (registers are the
// second buffer).
__global__ __launch_bounds__(256, 2) void gemm_bias_f32(
    const float* __restrict__ A,
    const float* __restrict__ Bw,
    const float* __restrict__ bias,
    float* __restrict__ C)
{
    __shared__ float As[BK * BM];   // 16 KB
    __shared__ float Bs[BK * BN];   // 32 KB

    const int tid = threadIdx.x;
    const int tx  = tid & 15;   // n direction (16 threads x 16 floats = 256)
    const int ty  = tid >> 4;   // m direction (16 threads x 8 floats = 128)
    const int m0  = blockIdx.y * BM;
    const int n0  = blockIdx.x * BN;

    float acc[8][16];
    #pragma unroll
    for (int i = 0; i < 8; i++)
        #pragma unroll
        for (int j = 0; j < 16; j++)
            acc[i][j] = 0.0f;

    // Staging mapping: thread loads 4 float4 from A (rows lrow+32p, p<4) and
    // 8 float4 from Bw (rows lrow+32p, p<8), k-cols lk..lk+3.
    const int lrow = tid >> 3;        // 0..31
    const int lk   = (tid & 7) * 4;   // 0,4,...,28
    const int q    = tid & 7;         // swizzle rho for this thread's k-rows

    const float* Aptr = A  + (size_t)(m0 + lrow) * I_DIM + lk;
    const float* Bptr = Bw + (size_t)(n0 + lrow) * I_DIM + lk;

    float4 av[4], bv[8];
    #pragma unroll
    for (int p = 0; p < 4; p++)
        av[p] = *(const float4*)(Aptr + (size_t)(p * 32) * I_DIM);
    #pragma unroll
    for (int p = 0; p < 8; p++)
        bv[p] = *(const float4*)(Bptr + (size_t)(p * 32) * I_DIM);

    for (int kt = 0; kt < KTILES; kt++) {
        __syncthreads();   // prior iteration's LDS reads complete

        #pragma unroll
        for (int p = 0; p < 4; p++) {
            const int r    = lrow + p * 32;
            const int base = (((r >> 2) ^ q) << 2) | (r & 3);
            As[(lk + 0) * BM + base] = av[p].x;
            As[(lk + 1) * BM + base] = av[p].y;
            As[(lk + 2) * BM + base] = av[p].z;
            As[(lk + 3) * BM + base] = av[p].w;
        }
        #pragma unroll
        for (int p = 0; p < 8; p++) {
            const int r    = lrow + p * 32;
            const int base = (((r >> 2) ^ q) << 2) | (r & 3);
            Bs[(lk + 0) * BN + base] = bv[p].x;
            Bs[(lk + 1) * BN + base] = bv[p].y;
            Bs[(lk + 2) * BN + base] = bv[p].z;
            Bs[(lk + 3) * BN + base] = bv[p].w;
        }

        __syncthreads();

        // Prefetch next tile into registers; latency hidden under compute.
        if (kt + 1 < KTILES) {
            const int k0 = (kt + 1) * BK;
            #pragma unroll
            for (int p = 0; p < 4; p++)
                av[p] = *(const float4*)(Aptr + (size_t)(p * 32) * I_DIM + k0);
            #pragma unroll
            for (int p = 0; p < 8; p++)
                bv[p] = *(const float4*)(Bptr + (size_t)(p * 32) * I_DIM + k0);
        }

        const float4* As4 = (const float4*)As;
        const float4* Bs4 = (const float4*)Bs;
        for (int kk = 0; kk < BK; kk += 4) {
            const int rho = (kk >> 2) & 7;
            #pragma unroll
            for (int kj = 0; kj < 4; kj++) {
                const int k = kk + kj;
                float4 a0 = As4[k * (BM / 4) + ((ty * 2)     ^ rho)];
                float4 a1 = As4[k * (BM / 4) + ((ty * 2 + 1) ^ rho)];
                float4 b0 = Bs4[k * (BN / 4) + ( tx        ^ rho)];
                float4 b1 = Bs4[k * (BN / 4) + ((16 + tx)  ^ rho)];
                float4 b2 = Bs4[k * (BN / 4) + ((32 + tx)  ^ rho)];
                float4 b3 = Bs4[k * (BN / 4) + ((48 + tx)  ^ rho)];
                float a[8]  = {a0.x, a0.y, a0.z, a0.w, a1.x, a1.y, a1.z, a1.w};
                float b[16] = {b0.x, b0.y, b0.z, b0.w, b1.x, b1.y, b1.z, b1.w,
                               b2.x, b2.y, b2.z, b2.w, b3.x, b3.y, b3.z, b3.w};
                #pragma unroll
                for (int i = 0; i < 8; i++)
                    #pragma unroll
                    for (int j = 0; j < 16; j++)
                        acc[i][j] = fmaf(a[i], b[j], acc[i][j]);
            }
        }
    }

    // Epilogue: bias + store. Column segments: n0 + 64*s + tx*4, s = 0..3.
    float4 bc[4];
    #pragma unroll
    for (int s = 0; s < 4; s++)
        bc[s] = *(const float4*)(bias + n0 + 64 * s + tx * 4);

    #pragma unroll
    for (int i = 0; i < 8; i++) {
        const int m = m0 + ty * 8 + i;
        float* cp = C + (size_t)m * H_DIM + n0 + tx * 4;
        #pragma unroll
        for (int s = 0; s < 4; s++) {
            float4 o;
            o.x = acc[i][4 * s + 0] + bc[s].x;
            o.y = acc[i][4 * s + 1] + bc[s].y;
            o.z = acc[i][4 * s + 2] + bc[s].z;
            o.w = acc[i][4 * s + 3] + bc[s].w;
            *(float4*)(cp + 64 * s) = o;
        }
    }
}

// LIF scan over T. One thread per neuron (b, j); n = B*H neurons.
// v <- v/2 + h_t ; s = (v >= 1) ; v <- s ? 0 : v
// Reverted to the round-0 known-good form (96 us): 16-deep load batch,
// plain stores. The 32-deep ping-pong + nontemporal stores regressed
// (likely outstanding-vmem pressure near the vmcnt=63 cap).
#define SCAN_UNROLL 16
__global__ __launch_bounds__(256) void lif_scan(
    const float* __restrict__ h,
    float* __restrict__ out)
{
    const int n   = B_DIM * H_DIM;   // 65536
    const int idx = blockIdx.x * 256 + threadIdx.x;
    const float* hp = h + idx;
    float* op = out + idx;

    float v = 0.0f;
    for (int t0 = 0; t0 < T_STEPS; t0 += SCAN_UNROLL) {
        float hv[SCAN_UNROLL];
        #pragma unroll
        for (int i = 0; i < SCAN_UNROLL; i++)
            hv[i] = hp[(size_t)(t0 + i) * n];

        float s[SCAN_UNROLL];
        #pragma unroll
        for (int i = 0; i < SCAN_UNROLL; i++) {
            v = 0.5f * v + hv[i];
            const bool fire = (v >= 1.0f);
            s[i] = fire ? 1.0f : 0.0f;
            v    = fire ? 0.0f : v;
        }

        #pragma unroll
        for (int i = 0; i < SCAN_UNROLL; i++)
            op[(size_t)(t0 + i) * n] = s[i];
    }
}

extern "C" void kernel_launch(void* const* d_in, const int* in_sizes, int n_in,
                              void* d_out, int out_size, void* d_ws, size_t ws_size,
                              hipStream_t stream) {
    const float* x = (const float*)d_in[0];   // (T, B, I) fp32
    const float* W = (const float*)d_in[1];   // (H, I)    fp32
    const float* b = (const float*)d_in[2];   // (H,)      fp32
    float* out = (float*)d_out;               // (T, B, H) fp32 spikes
    float* h   = (float*)d_ws;                // (T*B, H) fp32 scratch = 64 MB

    dim3 grid(H_DIM / BN, M_DIM / BM);        // (2, 256) = 512 blocks, 2/CU
    gemm_bias_f32<<<grid, 256, 0, stream>>>(x, W, b, h);

    lif_scan<<<(B_DIM * H_DIM) / 256, 256, 0, stream>>>(h, out);
}